// Round 10
// baseline (76.662 us; speedup 1.0000x reference)
//
#include <hip/hip_runtime.h>
#include <hip/hip_bf16.h>
#include <math.h>

#define D 768
#define NCLS 96
#define M 8192            // 32*256 tokens
#define EPS 1e-5f
#define LSTR 256          // list row stride (max tokens/class ~160 << 256)

// gram geometry (proven round-3)
#define KB 384
#define SEGR 48           // KB/8 16B segments per row-chunk
#define MAXR 160          // max rows per class (dict + tokens)
#define DYN_B (MAXR * KB * 2)   // 122880 B dynamic LDS

typedef __attribute__((ext_vector_type(8))) short bf16x8;
typedef __attribute__((ext_vector_type(4))) float f32x4;

// ---------------- kA: LN->token-order bf16 (blocks 0..2047) || lists+dict (2048..2143)
__global__ __launch_bounds__(256) void kA(const float* __restrict__ x,
        const float* __restrict__ cdic, const float* __restrict__ gamma,
        const float* __restrict__ beta, const int* __restrict__ labels,
        __hip_bfloat16* __restrict__ tokb, __hip_bfloat16* __restrict__ dicb,
        int* __restrict__ list, int* __restrict__ counts,
        unsigned int* __restrict__ ticket) {
    int bid = blockIdx.x, tid = threadIdx.x, wave = tid >> 6, lane = tid & 63;
    if (bid < 2048) {
        // ---- LayerNorm row -> tokb[row] (coalesced, token order; r3 body sans perm)
        int row = bid * 4 + wave;
        const float* xr = x + (size_t)row * D;
        float4 v[3];
        float s = 0.f, sq = 0.f;
#pragma unroll
        for (int t = 0; t < 3; ++t) {
            v[t] = *(const float4*)(xr + (lane + 64 * t) * 4);
            s  += v[t].x + v[t].y + v[t].z + v[t].w;
            sq += v[t].x * v[t].x + v[t].y * v[t].y + v[t].z * v[t].z + v[t].w * v[t].w;
        }
#pragma unroll
        for (int o = 32; o; o >>= 1) { s += __shfl_xor(s, o); sq += __shfl_xor(sq, o); }
        float mu   = s / (float)D;
        float var  = sq / (float)D - mu * mu;
        float rstd = rsqrtf(var + EPS);
        unsigned short* orow = (unsigned short*)tokb + (size_t)row * D;
#pragma unroll
        for (int t = 0; t < 3; ++t) {
            int base = (lane + 64 * t) * 4;
            float4 g4 = *(const float4*)(gamma + base);
            float4 b4 = *(const float4*)(beta + base);
            float f0 = (v[t].x - mu) * rstd * g4.x + b4.x;
            float f1 = (v[t].y - mu) * rstd * g4.y + b4.y;
            float f2 = (v[t].z - mu) * rstd * g4.z + b4.z;
            float f3 = (v[t].w - mu) * rstd * g4.w + b4.w;
            __hip_bfloat16 h0 = __float2bfloat16(f0), h1 = __float2bfloat16(f1);
            __hip_bfloat16 h2 = __float2bfloat16(f2), h3 = __float2bfloat16(f3);
            ushort4 u;
            u.x = *(unsigned short*)&h0; u.y = *(unsigned short*)&h1;
            u.z = *(unsigned short*)&h2; u.w = *(unsigned short*)&h3;
            *(ushort4*)(orow + base) = u;
        }
    } else {
        // ---- per-class list + count + dict bf16 copy (labels read from global/L2)
        int c = bid - 2048;
        __shared__ int ccnt[128];
        __shared__ int cbase[128];
        if (c == 0 && tid == 0) *ticket = 0u;   // reset finish ticket each call
        for (int ch = wave; ch < 128; ch += 4) {
            int lab = labels[ch * 64 + lane];
            unsigned long long meq = __ballot(lab == c);
            if (lane == 0) ccnt[ch] = __popcll(meq);
        }
        __syncthreads();
        if (wave == 0) {
            int v0 = ccnt[lane], v1 = ccnt[64 + lane];
            int s0 = v0;
#pragma unroll
            for (int o = 1; o < 64; o <<= 1) { int t0 = __shfl_up(s0, o); if (lane >= o) s0 += t0; }
            int tot0 = __shfl(s0, 63);
            int s1 = v1;
#pragma unroll
            for (int o = 1; o < 64; o <<= 1) { int t1 = __shfl_up(s1, o); if (lane >= o) s1 += t1; }
            cbase[lane] = s0 - v0;
            cbase[64 + lane] = tot0 + s1 - v1;
            if (lane == 63) counts[c] = tot0 + s1;
        }
        __syncthreads();
        for (int ch = wave; ch < 128; ch += 4) {
            int m = ch * 64 + lane;
            bool match = (labels[m] == c);
            unsigned long long mask = __ballot(match);
            int pre = __popcll(mask & ((1ull << lane) - 1ull));
            if (match) list[c * LSTR + cbase[ch] + pre] = m;
        }
        for (int t = tid; t < D; t += 256)
            dicb[(size_t)c * D + t] = __float2bfloat16(cdic[c * D + t]);
    }
}

// ---------------- kB: gram (blocks 0..95, list-gather) || cd (96..190) ----------
__global__ __launch_bounds__(256) void kB(const __hip_bfloat16* __restrict__ tokbh,
        const __hip_bfloat16* __restrict__ dicbh, const float* __restrict__ cdic,
        const float* __restrict__ gamma, const float* __restrict__ beta,
        const int* __restrict__ list, const int* __restrict__ counts,
        float* __restrict__ posp, float* __restrict__ cd) {
    int bid = blockIdx.x, tid = threadIdx.x, wave = tid >> 6, lane = tid & 63;
    const unsigned short* tok = (const unsigned short*)tokbh;

    if (bid < NCLS) {
        // -------- positive gram (r3 proven body; staging now list-gathered) -----
        int c = bid;
        const unsigned short* dic = (const unsigned short*)dicbh + (size_t)c * D;
        const int* lst = list + c * LSTR;
        extern __shared__ unsigned short sh[];
        int nc = counts[c] + 1;
        int ntile = (nc + 31) >> 5;
        int nr = ntile << 5;
        int tott = ntile * (ntile + 1) / 2;
        int s_ti[4], s_tj[4];
#pragma unroll
        for (int slot = 0; slot < 4; ++slot) {
            int t = wave + slot * 4;
            int ti = 0, rem = t, span = ntile;
            if (t < tott) {
                while (rem >= span) { rem -= span; --span; ++ti; }
                s_ti[slot] = ti; s_tj[slot] = ti + rem;
            } else { s_ti[slot] = 0; s_tj[slot] = 0; }
        }
        int r16 = lane & 15, sA = lane >> 4;
        int xr = r16 & 7;
        int e0 = (sA ^ xr) * 8;
        int e1 = ((sA + 4) ^ xr) * 8;
        f32x4 acc[4][4];
#pragma unroll
        for (int s = 0; s < 4; ++s)
#pragma unroll
            for (int q = 0; q < 4; ++q) acc[s][q] = f32x4{0.f, 0.f, 0.f, 0.f};
        for (int kc = 0; kc < D; kc += KB) {
            __syncthreads();
            int totseg = nr * SEGR;
            for (int seg = tid; seg < totseg; seg += 256) {
                int r = seg / SEGR, s = seg - r * SEGR;
                uint4 v = {0u, 0u, 0u, 0u};
                if (r < nc) {
                    const unsigned short* src = (r == 0)
                        ? dic : (tok + (size_t)lst[r - 1] * D);
                    v = *(const uint4*)(src + kc + s * 8);
                }
                *(uint4*)(sh + r * KB + (s ^ (r & 7)) * 8) = v;
            }
            __syncthreads();
#pragma unroll
            for (int slot = 0; slot < 4; ++slot) {
                if (wave + slot * 4 >= tott) continue;
                int ti = s_ti[slot], tj = s_tj[slot];
                const unsigned short* pa0 = sh + (ti * 32 + r16) * KB;
                const unsigned short* pa1 = pa0 + 16 * KB;
                const unsigned short* pb0 = sh + (tj * 32 + r16) * KB;
                const unsigned short* pb1 = pb0 + 16 * KB;
#pragma unroll
                for (int ks = 0; ks < KB / 32; ++ks) {
                    int ko = (ks >> 1) * 64 + ((ks & 1) ? e1 : e0);
                    bf16x8 a0 = *(const bf16x8*)(pa0 + ko);
                    bf16x8 a1 = *(const bf16x8*)(pa1 + ko);
                    bf16x8 b0 = *(const bf16x8*)(pb0 + ko);
                    bf16x8 b1 = *(const bf16x8*)(pb1 + ko);
                    acc[slot][0] = __builtin_amdgcn_mfma_f32_16x16x32_bf16(a0, b0, acc[slot][0], 0, 0, 0);
                    acc[slot][1] = __builtin_amdgcn_mfma_f32_16x16x32_bf16(a0, b1, acc[slot][1], 0, 0, 0);
                    acc[slot][2] = __builtin_amdgcn_mfma_f32_16x16x32_bf16(a1, b0, acc[slot][2], 0, 0, 0);
                    acc[slot][3] = __builtin_amdgcn_mfma_f32_16x16x32_bf16(a1, b1, acc[slot][3], 0, 0, 0);
                }
            }
        }
        const float inv = 1.f / (float)D;
        float tacc = 0.f;
        int rbase = sA * 4;
#pragma unroll
        for (int slot = 0; slot < 4; ++slot) {
            if (wave + slot * 4 >= tott) continue;
            int ti = s_ti[slot], tj = s_tj[slot];
            float w = (ti == tj) ? 1.f : 2.f;
#pragma unroll
            for (int fa = 0; fa < 2; ++fa)
#pragma unroll
                for (int fb = 0; fb < 2; ++fb)
#pragma unroll
                    for (int reg = 0; reg < 4; ++reg) {
                        int i = ti * 32 + fa * 16 + rbase + reg;
                        int j = tj * 32 + fb * 16 + r16;
                        if (i < nc && j < nc)
                            tacc += w * __expf(acc[slot][fa * 2 + fb][reg] * inv);
                    }
        }
#pragma unroll
        for (int o = 32; o; o >>= 1) tacc += __shfl_xor(tacc, o);
        __syncthreads();
        float* red = (float*)sh;
        if (lane == 0) red[wave] = tacc;
        __syncthreads();
        if (tid == 0) posp[c] = red[0] + red[1] + red[2] + red[3];
    } else {
        // -------- cd rows (r8 proven body; rows gathered via list) --------------
        int c = bid - 95;            // 1..95
        int n = counts[c];
        const int* lst = list + c * LSTR;
        float acc[3][4];
#pragma unroll
        for (int p = 0; p < 3; ++p)
#pragma unroll
            for (int e = 0; e < 4; ++e) acc[p][e] = 0.f;
        for (int r = wave; r < n; r += 4) {
            const unsigned short* rp = tok + (size_t)lst[r] * D + lane * 4;
#pragma unroll
            for (int p = 0; p < 3; ++p) {
                ushort4 u = *(const ushort4*)(rp + 256 * p);
                acc[p][0] += __bfloat162float(*(const __hip_bfloat16*)&u.x);
                acc[p][1] += __bfloat162float(*(const __hip_bfloat16*)&u.y);
                acc[p][2] += __bfloat162float(*(const __hip_bfloat16*)&u.z);
                acc[p][3] += __bfloat162float(*(const __hip_bfloat16*)&u.w);
            }
        }
        __shared__ float part[4][D];   // 12 KB static (separate from dynamic sh)
        __shared__ float red[8];
#pragma unroll
        for (int p = 0; p < 3; ++p)
#pragma unroll
            for (int e = 0; e < 4; ++e)
                part[wave][p * 256 + lane * 4 + e] = acc[p][e];
        __syncthreads();
        float s0 = (part[0][tid] + part[1][tid]) + (part[2][tid] + part[3][tid]);
        float s1 = (part[0][tid + 256] + part[1][tid + 256]) + (part[2][tid + 256] + part[3][tid + 256]);
        float s2 = (part[0][tid + 512] + part[1][tid + 512]) + (part[2][tid + 512] + part[3][tid + 512]);
        float invn = 1.f / ((float)n + 1.f);
        float c0 = cdic[c * D + tid], c1 = cdic[c * D + tid + 256], c2v = cdic[c * D + tid + 512];
        float u0 = c0 + 0.1f * (c0 + s0) * invn;
        float u1 = c1 + 0.1f * (c1 + s1) * invn;
        float u2 = c2v + 0.1f * (c2v + s2) * invn;
        float s = u0 + u1 + u2, sq = u0 * u0 + u1 * u1 + u2 * u2;
#pragma unroll
        for (int o = 32; o; o >>= 1) { s += __shfl_xor(s, o); sq += __shfl_xor(sq, o); }
        if (lane == 0) { red[wave] = s; red[4 + wave] = sq; }
        __syncthreads();
        if (tid == 0) {
            red[0] = red[0] + red[1] + red[2] + red[3];
            red[4] = red[4] + red[5] + red[6] + red[7];
        }
        __syncthreads();
        float mu   = red[0] / (float)D;
        float var  = red[4] / (float)D - mu * mu;
        float rstd = rsqrtf(var + EPS);
        float* outr = cd + (size_t)(c - 1) * D;
        outr[tid]       = (u0 - mu) * rstd * gamma[tid]       + beta[tid];
        outr[tid + 256] = (u1 - mu) * rstd * gamma[tid + 256] + beta[tid + 256];
        outr[tid + 512] = (u2 - mu) * rstd * gamma[tid + 512] + beta[tid + 512];
    }
}

// ---------------- kC: neg gram + ticket-gated final loss (proven r6-r9) ---------
__global__ __launch_bounds__(256) void kC(const float* __restrict__ cd,
        const float* __restrict__ posp, unsigned int* __restrict__ negbits,
        unsigned int* __restrict__ ticket, float* __restrict__ out) {
    int i = blockIdx.x;    // 0..94
    int tid = threadIdx.x, wave = tid >> 6, lane = tid & 63;
    __shared__ float rowi[D];
    __shared__ float red[4];
    __shared__ int winner;
    for (int t = tid; t < D; t += 256) rowi[t] = cd[(size_t)i * D + t];
    __syncthreads();
    float acc = 0.f;
    for (int j = wave; j < 95; j += 4) {
        const float* rj = cd + (size_t)j * D;
        float dot = 0.f;
#pragma unroll
        for (int t = 0; t < 12; ++t) dot += rowi[lane + 64 * t] * rj[lane + 64 * t];
#pragma unroll
        for (int o = 32; o; o >>= 1) dot += __shfl_xor(dot, o);
        if (lane == 0) acc += __expf(dot * (1.f / (float)D));
    }
    if (lane == 0) red[wave] = acc;
    __syncthreads();
    if (tid == 0) {
        float val = red[0] + red[1] + red[2] + red[3];
        atomicExch(&negbits[i], __float_as_uint(val));   // device-scope publish
        __threadfence();
        winner = (atomicAdd(ticket, 1u) == 94u) ? 1 : 0; // 95th finisher wins
    }
    __syncthreads();
    if (winner && wave == 0) {
        __threadfence();                                 // acquire others' publishes
        double ng = (lane < 95)
            ? (double)__uint_as_float(atomicOr(&negbits[lane], 0u)) : 0.0;
        if (lane < 31)
            ng += (double)__uint_as_float(atomicOr(&negbits[64 + lane], 0u));
        double p = (double)posp[lane];
        if (lane < 32) p += (double)posp[64 + lane];
#pragma unroll
        for (int o = 32; o; o >>= 1) {
            ng += __shfl_xor(ng, o);
            p  += __shfl_xor(p, o);
        }
        if (lane == 0) out[0] = (float)(log(ng) - log(p));
    }
}

extern "C" void kernel_launch(void* const* d_in, const int* in_sizes, int n_in,
                              void* d_out, int out_size, void* d_ws, size_t ws_size,
                              hipStream_t stream) {
    const float* input_f  = (const float*)d_in[0];
    const float* char_dic = (const float*)d_in[1];
    const float* gamma    = (const float*)d_in[2];
    const float* beta     = (const float*)d_in[3];
    const int*   target   = (const int*)d_in[4];
    float* out = (float*)d_out;

    char* ws = (char*)d_ws;
    size_t off = 0;
    auto carve = [&](size_t bytes) -> void* {
        void* p = ws + off;
        off = (off + bytes + 255) & ~(size_t)255;
        return p;
    };
    __hip_bfloat16* tokb = (__hip_bfloat16*)carve((size_t)M * D * 2);     // 12.6 MB
    __hip_bfloat16* dicb = (__hip_bfloat16*)carve((size_t)NCLS * D * 2);  // 147 KB
    int*          list    = (int*)  carve((size_t)NCLS * LSTR * 4);
    int*          counts  = (int*)  carve(NCLS * 4);
    float*        posp    = (float*)carve(NCLS * 4);
    float*        cd      = (float*)carve((size_t)95 * D * 4);
    unsigned int* negbits = (unsigned int*)carve(95 * 4);
    unsigned int* ticket  = (unsigned int*)carve(64);

    (void)hipFuncSetAttribute((const void*)kB,
            hipFuncAttributeMaxDynamicSharedMemorySize, DYN_B);

    kA<<<2048 + NCLS, 256, 0, stream>>>(input_f, char_dic, gamma, beta, target,
                                        tokb, dicb, list, counts, ticket);
    kB<<<NCLS + 95, 256, DYN_B, stream>>>(tokb, dicb, char_dic, gamma, beta,
                                          list, counts, posp, cd);
    kC<<<95, 256, 0, stream>>>(cd, posp, negbits, ticket, out);
}

// Round 11
// 55.484 us; speedup vs baseline: 1.3817x; 1.3817x over previous
//
#include <hip/hip_runtime.h>
#include <hip/hip_bf16.h>
#include <math.h>

#define D 768
#define NCLS 96
#define M 8192            // 32*256 tokens
#define NROWS (M + NCLS)  // 8288 grouped rows
#define EPS 1e-5f

// gram geometry (proven round-3)
#define KB 384
#define SEGR 48           // KB/8 16B segments per row-chunk
#define MAXR 160          // max rows per class (dict + tokens)
#define DYN_B (MAXR * KB * 2)   // 122880 B dynamic LDS

typedef __attribute__((ext_vector_type(8))) short bf16x8;
typedef __attribute__((ext_vector_type(4))) float f32x4;

// ---------------- K2: counts/gofs/perm + dict copy (round-3 proven) -------------
__global__ __launch_bounds__(256) void k2_lists(const int* __restrict__ labels,
        const float* __restrict__ cdic, int* __restrict__ perm,
        int* __restrict__ counts, int* __restrict__ gofs,
        __hip_bfloat16* __restrict__ xgb, unsigned int* __restrict__ ticket) {
    int c = blockIdx.x;
    int tid = threadIdx.x, wave = tid >> 6, lane = tid & 63;
    __shared__ int labs[M];
    __shared__ int ccnt[128];
    __shared__ int cbase[128];
    __shared__ int ltred[4];
    __shared__ int gsh;
    if (c == 0 && tid == 0) *ticket = 0u;     // reset finish ticket each call
    for (int t = tid; t < M / 4; t += 256)
        ((int4*)labs)[t] = ((const int4*)labels)[t];
    __syncthreads();
    int lt0 = 0;
    for (int ch = wave; ch < 128; ch += 4) {
        int lab = labs[ch * 64 + lane];
        unsigned long long meq = __ballot(lab == c);
        unsigned long long mlt = __ballot(lab < c);
        if (lane == 0) { ccnt[ch] = __popcll(meq); lt0 += __popcll(mlt); }
    }
    if (lane == 0) ltred[wave] = lt0;
    __syncthreads();
    if (wave == 0) {
        int v0 = ccnt[lane], v1 = ccnt[64 + lane];
        int s0 = v0;
#pragma unroll
        for (int o = 1; o < 64; o <<= 1) { int t0 = __shfl_up(s0, o); if (lane >= o) s0 += t0; }
        int tot0 = __shfl(s0, 63);
        int s1 = v1;
#pragma unroll
        for (int o = 1; o < 64; o <<= 1) { int t1 = __shfl_up(s1, o); if (lane >= o) s1 += t1; }
        cbase[lane] = s0 - v0;
        cbase[64 + lane] = tot0 + s1 - v1;
        if (lane == 63) {
            counts[c] = tot0 + s1;
            int g = c + ltred[0] + ltred[1] + ltred[2] + ltred[3];
            gofs[c] = g;
            gsh = g;
        }
    }
    __syncthreads();
    int g = gsh;
    for (int ch = wave; ch < 128; ch += 4) {
        int m = ch * 64 + lane;
        bool match = (labs[m] == c);
        unsigned long long mask = __ballot(match);
        int pre = __popcll(mask & ((1ull << lane) - 1ull));
        if (match) perm[m] = g + 1 + cbase[ch] + pre;
    }
    for (int t = tid; t < D; t += 256)
        xgb[(size_t)g * D + t] = __float2bfloat16(cdic[c * D + t]);
}

// ---------------- K1: LayerNorm + bf16 scatter (round-3 proven) -----------------
__global__ __launch_bounds__(256) void k1_layernorm(const float* __restrict__ x,
        const float* __restrict__ gamma, const float* __restrict__ beta,
        const int* __restrict__ perm, __hip_bfloat16* __restrict__ xgb) {
    int wave = threadIdx.x >> 6;
    int lane = threadIdx.x & 63;
    int row = blockIdx.x * 4 + wave;
    const float* xr = x + (size_t)row * D;
    float4 v[3];
    float s = 0.f, sq = 0.f;
#pragma unroll
    for (int t = 0; t < 3; ++t) {
        v[t] = *(const float4*)(xr + (lane + 64 * t) * 4);
        s  += v[t].x + v[t].y + v[t].z + v[t].w;
        sq += v[t].x * v[t].x + v[t].y * v[t].y + v[t].z * v[t].z + v[t].w * v[t].w;
    }
#pragma unroll
    for (int o = 32; o; o >>= 1) { s += __shfl_xor(s, o); sq += __shfl_xor(sq, o); }
    float mu   = s / (float)D;
    float var  = sq / (float)D - mu * mu;
    float rstd = rsqrtf(var + EPS);
    int dest = perm[row];
    unsigned short* orow = (unsigned short*)xgb + (size_t)dest * D;
#pragma unroll
    for (int t = 0; t < 3; ++t) {
        int base = (lane + 64 * t) * 4;
        float4 g4 = *(const float4*)(gamma + base);
        float4 b4 = *(const float4*)(beta + base);
        float f0 = (v[t].x - mu) * rstd * g4.x + b4.x;
        float f1 = (v[t].y - mu) * rstd * g4.y + b4.y;
        float f2 = (v[t].z - mu) * rstd * g4.z + b4.z;
        float f3 = (v[t].w - mu) * rstd * g4.w + b4.w;
        __hip_bfloat16 h0 = __float2bfloat16(f0), h1 = __float2bfloat16(f1);
        __hip_bfloat16 h2 = __float2bfloat16(f2), h3 = __float2bfloat16(f3);
        ushort4 u;
        u.x = *(unsigned short*)&h0; u.y = *(unsigned short*)&h1;
        u.z = *(unsigned short*)&h2; u.w = *(unsigned short*)&h3;
        *(ushort4*)(orow + base) = u;
    }
}

// ---------------- kB (512 threads): gram (blocks 0..95) || cd (96..190) ---------
// 8 waves/block: staging iterations halve, latency hiding doubles vs r9.
__global__ __launch_bounds__(512) void kB(const __hip_bfloat16* __restrict__ xgbh,
        const float* __restrict__ cdic, const float* __restrict__ gamma,
        const float* __restrict__ beta, const int* __restrict__ counts,
        const int* __restrict__ gofs, float* __restrict__ posp,
        float* __restrict__ cd) {
    int bid = blockIdx.x, tid = threadIdx.x, wave = tid >> 6, lane = tid & 63;

    if (bid < NCLS) {
        // -------- positive gram (r3 body, re-tiled for 8 waves x 2 slots) -------
        const unsigned short* xgb = (const unsigned short*)xgbh;
        int c = bid;
        extern __shared__ unsigned short sh[];
        int r0 = gofs[c];
        int nc = counts[c] + 1;
        int ntile = (nc + 31) >> 5;
        int nr = ntile << 5;
        int tott = ntile * (ntile + 1) / 2;      // <= 15 for ntile <= 5
        int s_ti[2], s_tj[2];
#pragma unroll
        for (int slot = 0; slot < 2; ++slot) {
            int t = wave + slot * 8;
            int ti = 0, rem = t, span = ntile;
            if (t < tott) {
                while (rem >= span) { rem -= span; --span; ++ti; }
                s_ti[slot] = ti; s_tj[slot] = ti + rem;
            } else { s_ti[slot] = 0; s_tj[slot] = 0; }
        }
        int r16 = lane & 15, sA = lane >> 4;
        int xr = r16 & 7;
        int e0 = (sA ^ xr) * 8;
        int e1 = ((sA + 4) ^ xr) * 8;
        f32x4 acc[2][4];
#pragma unroll
        for (int s = 0; s < 2; ++s)
#pragma unroll
            for (int q = 0; q < 4; ++q) acc[s][q] = f32x4{0.f, 0.f, 0.f, 0.f};
        for (int kc = 0; kc < D; kc += KB) {
            __syncthreads();
            int totseg = nr * SEGR;
            for (int seg = tid; seg < totseg; seg += 512) {
                int r = seg / SEGR, s = seg - r * SEGR;
                uint4 v = {0u, 0u, 0u, 0u};
                if (r < nc)
                    v = *(const uint4*)(xgb + (size_t)(r0 + r) * D + kc + s * 8);
                *(uint4*)(sh + r * KB + (s ^ (r & 7)) * 8) = v;
            }
            __syncthreads();
#pragma unroll
            for (int slot = 0; slot < 2; ++slot) {
                if (wave + slot * 8 >= tott) continue;
                int ti = s_ti[slot], tj = s_tj[slot];
                const unsigned short* pa0 = sh + (ti * 32 + r16) * KB;
                const unsigned short* pa1 = pa0 + 16 * KB;
                const unsigned short* pb0 = sh + (tj * 32 + r16) * KB;
                const unsigned short* pb1 = pb0 + 16 * KB;
#pragma unroll
                for (int ks = 0; ks < KB / 32; ++ks) {
                    int ko = (ks >> 1) * 64 + ((ks & 1) ? e1 : e0);
                    bf16x8 a0 = *(const bf16x8*)(pa0 + ko);
                    bf16x8 a1 = *(const bf16x8*)(pa1 + ko);
                    bf16x8 b0 = *(const bf16x8*)(pb0 + ko);
                    bf16x8 b1 = *(const bf16x8*)(pb1 + ko);
                    acc[slot][0] = __builtin_amdgcn_mfma_f32_16x16x32_bf16(a0, b0, acc[slot][0], 0, 0, 0);
                    acc[slot][1] = __builtin_amdgcn_mfma_f32_16x16x32_bf16(a0, b1, acc[slot][1], 0, 0, 0);
                    acc[slot][2] = __builtin_amdgcn_mfma_f32_16x16x32_bf16(a1, b0, acc[slot][2], 0, 0, 0);
                    acc[slot][3] = __builtin_amdgcn_mfma_f32_16x16x32_bf16(a1, b1, acc[slot][3], 0, 0, 0);
                }
            }
        }
        const float inv = 1.f / (float)D;
        float tacc = 0.f;
        int rbase = sA * 4;
#pragma unroll
        for (int slot = 0; slot < 2; ++slot) {
            if (wave + slot * 8 >= tott) continue;
            int ti = s_ti[slot], tj = s_tj[slot];
            float w = (ti == tj) ? 1.f : 2.f;
#pragma unroll
            for (int fa = 0; fa < 2; ++fa)
#pragma unroll
                for (int fb = 0; fb < 2; ++fb)
#pragma unroll
                    for (int reg = 0; reg < 4; ++reg) {
                        int i = ti * 32 + fa * 16 + rbase + reg;
                        int j = tj * 32 + fb * 16 + r16;
                        if (i < nc && j < nc)
                            tacc += w * __expf(acc[slot][fa * 2 + fb][reg] * inv);
                    }
        }
#pragma unroll
        for (int o = 32; o; o >>= 1) tacc += __shfl_xor(tacc, o);
        __syncthreads();
        float* red = (float*)sh;
        if (lane == 0) red[wave] = tacc;
        __syncthreads();
        if (tid == 0)
            posp[c] = ((red[0] + red[1]) + (red[2] + red[3]))
                    + ((red[4] + red[5]) + (red[6] + red[7]));
    } else {
        // -------- cd rows (r8 body, 8-wave row loop + 256-thread epilogue) ------
        int c = bid - 95;            // 1..95
        int n = counts[c];
        const unsigned short* rows = (const unsigned short*)xgbh + (size_t)(gofs[c] + 1) * D;
        float acc[3][4];
#pragma unroll
        for (int p = 0; p < 3; ++p)
#pragma unroll
            for (int e = 0; e < 4; ++e) acc[p][e] = 0.f;
        for (int r = wave; r < n; r += 8) {
            const unsigned short* rp = rows + (size_t)r * D + lane * 4;
#pragma unroll
            for (int p = 0; p < 3; ++p) {
                ushort4 u = *(const ushort4*)(rp + 256 * p);
                acc[p][0] += __bfloat162float(*(const __hip_bfloat16*)&u.x);
                acc[p][1] += __bfloat162float(*(const __hip_bfloat16*)&u.y);
                acc[p][2] += __bfloat162float(*(const __hip_bfloat16*)&u.z);
                acc[p][3] += __bfloat162float(*(const __hip_bfloat16*)&u.w);
            }
        }
        __shared__ float part[8][D];   // 24 KB static
        __shared__ float red[8];
#pragma unroll
        for (int p = 0; p < 3; ++p)
#pragma unroll
            for (int e = 0; e < 4; ++e)
                part[wave][p * 256 + lane * 4 + e] = acc[p][e];
        __syncthreads();
        float u0 = 0.f, u1 = 0.f, u2 = 0.f;
        if (tid < 256) {
            float s0 = 0.f, s1 = 0.f, s2 = 0.f;
#pragma unroll
            for (int w = 0; w < 8; ++w) {
                s0 += part[w][tid];
                s1 += part[w][tid + 256];
                s2 += part[w][tid + 512];
            }
            float invn = 1.f / ((float)n + 1.f);
            float c0 = cdic[c * D + tid], c1 = cdic[c * D + tid + 256], c2v = cdic[c * D + tid + 512];
            u0 = c0 + 0.1f * (c0 + s0) * invn;
            u1 = c1 + 0.1f * (c1 + s1) * invn;
            u2 = c2v + 0.1f * (c2v + s2) * invn;
            float s = u0 + u1 + u2, sq = u0 * u0 + u1 * u1 + u2 * u2;
#pragma unroll
            for (int o = 32; o; o >>= 1) { s += __shfl_xor(s, o); sq += __shfl_xor(sq, o); }
            if (lane == 0) { red[wave] = s; red[4 + wave] = sq; }
        }
        __syncthreads();
        if (tid == 0) {
            red[0] = red[0] + red[1] + red[2] + red[3];
            red[4] = red[4] + red[5] + red[6] + red[7];
        }
        __syncthreads();
        if (tid < 256) {
            float mu   = red[0] / (float)D;
            float var  = red[4] / (float)D - mu * mu;
            float rstd = rsqrtf(var + EPS);
            float* outr = cd + (size_t)(c - 1) * D;
            outr[tid]       = (u0 - mu) * rstd * gamma[tid]       + beta[tid];
            outr[tid + 256] = (u1 - mu) * rstd * gamma[tid + 256] + beta[tid + 256];
            outr[tid + 512] = (u2 - mu) * rstd * gamma[tid + 512] + beta[tid + 512];
        }
    }
}

// ---------------- kC: neg gram + ticket-gated final loss (proven r6-r9) ---------
__global__ __launch_bounds__(256) void kC(const float* __restrict__ cd,
        const float* __restrict__ posp, unsigned int* __restrict__ negbits,
        unsigned int* __restrict__ ticket, float* __restrict__ out) {
    int i = blockIdx.x;    // 0..94
    int tid = threadIdx.x, wave = tid >> 6, lane = tid & 63;
    __shared__ float rowi[D];
    __shared__ float red[4];
    __shared__ int winner;
    for (int t = tid; t < D; t += 256) rowi[t] = cd[(size_t)i * D + t];
    __syncthreads();
    float acc = 0.f;
    for (int j = wave; j < 95; j += 4) {
        const float* rj = cd + (size_t)j * D;
        float dot = 0.f;
#pragma unroll
        for (int t = 0; t < 12; ++t) dot += rowi[lane + 64 * t] * rj[lane + 64 * t];
#pragma unroll
        for (int o = 32; o; o >>= 1) dot += __shfl_xor(dot, o);
        if (lane == 0) acc += __expf(dot * (1.f / (float)D));
    }
    if (lane == 0) red[wave] = acc;
    __syncthreads();
    if (tid == 0) {
        float val = red[0] + red[1] + red[2] + red[3];
        atomicExch(&negbits[i], __float_as_uint(val));   // device-scope publish
        __threadfence();
        winner = (atomicAdd(ticket, 1u) == 94u) ? 1 : 0; // 95th finisher wins
    }
    __syncthreads();
    if (winner && wave == 0) {
        __threadfence();                                 // acquire others' publishes
        double ng = (lane < 95)
            ? (double)__uint_as_float(atomicOr(&negbits[lane], 0u)) : 0.0;
        if (lane < 31)
            ng += (double)__uint_as_float(atomicOr(&negbits[64 + lane], 0u));
        double p = (double)posp[lane];
        if (lane < 32) p += (double)posp[64 + lane];
#pragma unroll
        for (int o = 32; o; o >>= 1) {
            ng += __shfl_xor(ng, o);
            p  += __shfl_xor(p, o);
        }
        if (lane == 0) out[0] = (float)(log(ng) - log(p));
    }
}

extern "C" void kernel_launch(void* const* d_in, const int* in_sizes, int n_in,
                              void* d_out, int out_size, void* d_ws, size_t ws_size,
                              hipStream_t stream) {
    const float* input_f  = (const float*)d_in[0];
    const float* char_dic = (const float*)d_in[1];
    const float* gamma    = (const float*)d_in[2];
    const float* beta     = (const float*)d_in[3];
    const int*   target   = (const int*)d_in[4];
    float* out = (float*)d_out;

    char* ws = (char*)d_ws;
    size_t off = 0;
    auto carve = [&](size_t bytes) -> void* {
        void* p = ws + off;
        off = (off + bytes + 255) & ~(size_t)255;
        return p;
    };
    __hip_bfloat16* xgb = (__hip_bfloat16*)carve((size_t)(NROWS + 32) * D * 2); // 12.8 MB
    int*          perm    = (int*)  carve((size_t)M * 4);
    int*          counts  = (int*)  carve(NCLS * 4);
    int*          gofs    = (int*)  carve(NCLS * 4);
    float*        posp    = (float*)carve(NCLS * 4);
    float*        cd      = (float*)carve((size_t)95 * D * 4);
    unsigned int* negbits = (unsigned int*)carve(95 * 4);
    unsigned int* ticket  = (unsigned int*)carve(64);

    (void)hipFuncSetAttribute((const void*)kB,
            hipFuncAttributeMaxDynamicSharedMemorySize, DYN_B);

    k2_lists<<<NCLS, 256, 0, stream>>>(target, char_dic, perm, counts, gofs, xgb, ticket);
    k1_layernorm<<<M / 4, 256, 0, stream>>>(input_f, gamma, beta, perm, xgb);
    kB<<<NCLS + 95, 512, DYN_B, stream>>>(xgb, char_dic, gamma, beta, counts, gofs, posp, cd);
    kC<<<95, 256, 0, stream>>>(cd, posp, negbits, ticket, out);
}